// Round 2
// baseline (469.414 us; speedup 1.0000x reference)
//
#include <hip/hip_runtime.h>

#define NIN  20
#define NHID 6
#define NOUT 6
#define RPB  256   // rows per block (= block size, 1 row/thread)
#define PAD  21    // padded LDS row stride in dwords; odd => 2-way (free) banks

__device__ __forceinline__ float fsig(float t) {
    // sigmoid(t) = 1/(1+exp(-t)); v_exp_f32 + v_rcp_f32, ~1e-7 rel error
    return __builtin_amdgcn_rcpf(1.0f + __expf(-t));
}

__global__ __launch_bounds__(256, 4)
void mlp_fused(const float* __restrict__ x,
               const float* __restrict__ W1,
               const float* __restrict__ W2,
               const float* __restrict__ W5,
               float* __restrict__ out,
               int nrows)
{
    __shared__ float sx[RPB * PAD];          // 21504 B -> 7 blocks/CU

    const int t = threadIdx.x;
    const long long blk_row0 = (long long)blockIdx.x * RPB;
    const int rows_here = min(RPB, nrows - (int)min((long long)nrows, blk_row0));

    // ---- stage 256 rows of x (20 KB) into LDS, fully coalesced ----
    // chunk = 256*20 floats = 1280 float4; lane stride 16 B per instruction.
    const float4* __restrict__ xp4 = (const float4*)(x + blk_row0 * NIN);
    const int n4 = rows_here * 5;            // 4|20: no float4 crosses a row
#pragma unroll
    for (int k = 0; k < 5; ++k) {
        const int i = t + RPB * k;           // float4 index within chunk
        if (i < n4) {
            float4 v = xp4[i];
            const int r = i / 5;
            const int c = 4 * (i % 5);
            float* d = &sx[r * PAD + c];
            d[0] = v.x; d[1] = v.y; d[2] = v.z; d[3] = v.w;
        }
    }
    __syncthreads();

    if (t >= rows_here) return;

    // ---- one row per thread; x row from LDS (2-way banks = free) ----
    float xr[NIN];
#pragma unroll
    for (int k = 0; k < NIN; ++k) xr[k] = sx[t * PAD + k];

    // Weights: uniform pointer + constant offsets -> s_load / SGPR operands.
    // layer 1: [20] -> [6], sigmoid
    float h[NHID];
#pragma unroll
    for (int j = 0; j < NHID; ++j) {
        float a = 0.0f;
#pragma unroll
        for (int k = 0; k < NIN; ++k) a = fmaf(xr[k], W1[j * NIN + k], a);
        h[j] = fsig(a);
    }

    // layer 2: [6] -> [6], sigmoid
    float g[NHID];
#pragma unroll
    for (int j = 0; j < NHID; ++j) {
        float a = 0.0f;
#pragma unroll
        for (int k = 0; k < NHID; ++k) a = fmaf(h[k], W2[j * NHID + k], a);
        g[j] = fsig(a);
    }

    // layer 3: [6] -> [6], no activation
    float o[NOUT];
#pragma unroll
    for (int j = 0; j < NOUT; ++j) {
        float a = 0.0f;
#pragma unroll
        for (int k = 0; k < NHID; ++k) a = fmaf(g[k], W5[j * NHID + k], a);
        o[j] = a;
    }

    // 24 B/row, 8 B-aligned -> 3x float2 stores, contiguous across the wave
    float2* __restrict__ op = (float2*)(out + (blk_row0 + t) * NOUT);
    op[0] = make_float2(o[0], o[1]);
    op[1] = make_float2(o[2], o[3]);
    op[2] = make_float2(o[4], o[5]);
}

extern "C" void kernel_launch(void* const* d_in, const int* in_sizes, int n_in,
                              void* d_out, int out_size, void* d_ws, size_t ws_size,
                              hipStream_t stream) {
    const float* x  = (const float*)d_in[0];
    const float* W1 = (const float*)d_in[1];
    const float* W2 = (const float*)d_in[2];
    const float* W5 = (const float*)d_in[3];
    float* out = (float*)d_out;

    const int nrows = in_sizes[0] / NIN;                 // 4194304
    const int grid  = (nrows + RPB - 1) / RPB;           // 16384
    mlp_fused<<<grid, RPB, 0, stream>>>(x, W1, W2, W5, out, nrows);
}